// Round 5
// baseline (4950.095 us; speedup 1.0000x reference)
//
#include <hip/hip_runtime.h>
#include <hip/hip_cooperative_groups.h>
#include <hip/hip_bf16.h>
#include <cmath>

namespace cg = cooperative_groups;

// Problem constants
#define N_   128
#define T_   64
#define D_   1024
#define H_   1024
#define G4_  4096   // 4*H
#define KTOT 3072   // D + H + H (segments: x | h | attn)

typedef short bf16x8 __attribute__((ext_vector_type(8)));
typedef float f32x4  __attribute__((ext_vector_type(4)));

__device__ __forceinline__ unsigned short f2bf(float f) {
    union { float f; unsigned int u; } v; v.f = f;
    unsigned int r = (v.u + 0x7FFFu + ((v.u >> 16) & 1u)) >> 16;  // RNE
    return (unsigned short)r;
}

// ---------------------------------------------------------------- prep ----

__global__ void k_convert_x(const float* __restrict__ x, unsigned short* __restrict__ xbf) {
    long i = ((long)blockIdx.x * blockDim.x + threadIdx.x) * 8;
    float4 a = *(const float4*)(x + i);
    float4 b = *(const float4*)(x + i + 4);
    union { unsigned short s[8]; uint4 v; } o;
    o.s[0] = f2bf(a.x); o.s[1] = f2bf(a.y); o.s[2] = f2bf(a.z); o.s[3] = f2bf(a.w);
    o.s[4] = f2bf(b.x); o.s[5] = f2bf(b.y); o.s[6] = f2bf(b.z); o.s[7] = f2bf(b.w);
    *(uint4*)(xbf + i) = o.v;
}

// out[c][ocoff + r] = bf16(in[r][c]); in is R x C (f32), out rows have stride ors.
__global__ void k_transpose(const float* __restrict__ in, unsigned short* __restrict__ out,
                            int R, int C, long ors, long ocoff) {
    __shared__ float tile[32][33];
    int c0 = blockIdx.x * 32, r0 = blockIdx.y * 32;
    int tx = threadIdx.x, ty = threadIdx.y;  // (32, 8)
    for (int yy = ty; yy < 32; yy += 8) {
        int r = r0 + yy, c = c0 + tx;
        if (r < R && c < C) tile[yy][tx] = in[(long)r * C + c];
    }
    __syncthreads();
    for (int yy = ty; yy < 32; yy += 8) {
        int oc = c0 + yy;    // out row  (orig col)
        int orr = r0 + tx;   // out col  (orig row)
        if (oc < C && orr < R) out[(long)oc * ors + ocoff + orr] = f2bf(tile[tx][yy]);
    }
}

// h0[n][j] = mean_p A[n][j][p];  c0 = h0;  also bf16 copy
__global__ void k_h0(const float* __restrict__ A, float* __restrict__ h,
                     float* __restrict__ c, unsigned short* __restrict__ hbf) {
    long id = (long)blockIdx.x * blockDim.x + threadIdx.x;  // 0 .. 128*1024-1
    const float4* ap = (const float4*)(A + id * 16);
    float s = 0.f;
    #pragma unroll
    for (int q = 0; q < 4; q++) { float4 v = ap[q]; s += v.x + v.y + v.z + v.w; }
    float m = s * (1.0f / 16.0f);
    h[id] = m; c[id] = m; hbf[id] = f2bf(m);
}

// ------------------------------------------------------ persistent kernel ----
// 256 blocks x 512 threads, cooperative. Per step:
//   phase A (blocks 0..127): scores -> softmax -> attn for n = bid  (fp32)
//   grid.sync()
//   phase B (all blocks): R3 k_step body — K-split-8 GEMM + LDS reduce + LSTM
//   grid.sync()
// jt = bid%64 keeps XCD = bid%8 = jt%8: per-XCD Wt slice (3.1MB) re-read every
// step from the same L2.
__global__ __launch_bounds__(512)
void k_persist(const unsigned short* __restrict__ xbf,   // [N][T][D]
               unsigned short* hbf0, unsigned short* hbf1,
               unsigned short* attnbf,
               const unsigned short* __restrict__ Wt,    // [4096][3072]
               const float* __restrict__ bvec,
               const float* __restrict__ A,              // [N][H][16]
               float* hbuf, float* cbuf,
               float* __restrict__ out, int /*unused*/) {
    cg::grid_group grid = cg::this_grid();
    int bid = blockIdx.x;
    int tid = threadIdx.x;
    int wave = tid >> 6, lane = tid & 63;

    __shared__ float red[4][64][33];
    __shared__ float sred[8][16];
    __shared__ float wsh[16];

    for (int t = 0; t < T_; t++) {
        const unsigned short* hin = (t & 1) ? hbf1 : hbf0;
        unsigned short* hout      = (t & 1) ? hbf0 : hbf1;

        // ---------------- phase A: attention ----------------
        if (bid < N_) {
            int n = bid;
            const float* An = A + (long)n * (H_ * 16);
            const float* hn = hbuf + (long)n * H_;
            int h0 = tid * 2;
            float4 row[2][4];
            float acc[16];
            #pragma unroll
            for (int p = 0; p < 16; p++) acc[p] = 0.f;
            #pragma unroll
            for (int u = 0; u < 2; u++) {
                float hv = hn[h0 + u];
                const float4* ap = (const float4*)(An + (long)(h0 + u) * 16);
                #pragma unroll
                for (int q = 0; q < 4; q++) {
                    float4 v = ap[q];
                    row[u][q] = v;
                    acc[q*4+0] += hv * v.x; acc[q*4+1] += hv * v.y;
                    acc[q*4+2] += hv * v.z; acc[q*4+3] += hv * v.w;
                }
            }
            #pragma unroll
            for (int off = 32; off > 0; off >>= 1) {
                #pragma unroll
                for (int p = 0; p < 16; p++) acc[p] += __shfl_xor(acc[p], off);
            }
            if (lane == 0) {
                #pragma unroll
                for (int p = 0; p < 16; p++) sred[wave][p] = acc[p];
            }
            __syncthreads();
            if (tid < 16) {
                float s = 0.f;
                #pragma unroll
                for (int w = 0; w < 8; w++) s += sred[w][tid];
                wsh[tid] = s * (1.0f / 32.0f);   // /sqrt(H)
            }
            __syncthreads();
            float w[16];
            float m = -1e30f;
            #pragma unroll
            for (int p = 0; p < 16; p++) { w[p] = wsh[p]; m = fmaxf(m, w[p]); }
            float sum = 0.f;
            #pragma unroll
            for (int p = 0; p < 16; p++) { w[p] = expf(w[p] - m); sum += w[p]; }
            float inv = 1.0f / sum;
            #pragma unroll
            for (int p = 0; p < 16; p++) w[p] *= inv;
            #pragma unroll
            for (int u = 0; u < 2; u++) {
                float s = 0.f;
                #pragma unroll
                for (int q = 0; q < 4; q++) {
                    float4 v = row[u][q];
                    s += w[q*4+0]*v.x + w[q*4+1]*v.y + w[q*4+2]*v.z + w[q*4+3]*v.w;
                }
                attnbf[(long)n * H_ + h0 + u] = f2bf(s);
            }
            __syncthreads();   // protect sred/wsh before next use
        }
        grid.sync();

        // ---------------- phase B: GEMM + LSTM (R3 k_step body) ----------------
        {
            int cl = lane & 15;
            int kg = lane >> 4;
            int jt = bid & 63;
            int rt = bid >> 6;
            int colbase = jt * 16;
            int rowbase = rt * 32;

            f32x4 acc[4][2];
            #pragma unroll
            for (int g = 0; g < 4; g++) {
                acc[g][0] = (f32x4){0.f,0.f,0.f,0.f};
                acc[g][1] = (f32x4){0.f,0.f,0.f,0.f};
            }

            int kw = wave * 128;
            int r0 = rowbase + cl;
            const unsigned short* a0[3];
            a0[0] = xbf    + ((long)r0 * T_ + t) * D_ + kw + kg * 8;
            a0[1] = hin    + (long)r0 * H_          + kw + kg * 8;
            a0[2] = attnbf + (long)r0 * H_          + kw + kg * 8;
            const long rs2[3] = {16L * T_ * D_, 16L * H_, 16L * H_};

            const unsigned short* bp[4];
            #pragma unroll
            for (int g = 0; g < 4; g++)
                bp[g] = Wt + (long)(g * 1024 + colbase + cl) * KTOT + kw + kg * 8;

            #pragma unroll
            for (int seg = 0; seg < 3; seg++) {
                const unsigned short* ab = a0[seg];
                long rstep = rs2[seg];
                long koff = (long)seg * 1024;
                #pragma unroll
                for (int k0 = 0; k0 < 128; k0 += 32) {
                    bf16x8 a1 = *(const bf16x8*)(ab + k0);
                    bf16x8 a2 = *(const bf16x8*)(ab + rstep + k0);
                    #pragma unroll
                    for (int g = 0; g < 4; g++) {
                        bf16x8 bb = *(const bf16x8*)(bp[g] + koff + k0);
                        acc[g][0] = __builtin_amdgcn_mfma_f32_16x16x32_bf16(a1, bb, acc[g][0], 0, 0, 0);
                        acc[g][1] = __builtin_amdgcn_mfma_f32_16x16x32_bf16(a2, bb, acc[g][1], 0, 0, 0);
                    }
                }
            }

            // cross-wave K reduction (pairwise)
            if (wave >= 4) {
                #pragma unroll
                for (int g = 0; g < 4; g++)
                    #pragma unroll
                    for (int rh = 0; rh < 2; rh++)
                        #pragma unroll
                        for (int v = 0; v < 4; v++)
                            red[wave - 4][lane][g*8 + rh*4 + v] = acc[g][rh][v];
            }
            __syncthreads();
            if (wave < 4) {
                #pragma unroll
                for (int g = 0; g < 4; g++)
                    #pragma unroll
                    for (int rh = 0; rh < 2; rh++)
                        #pragma unroll
                        for (int v = 0; v < 4; v++)
                            acc[g][rh][v] += red[wave][lane][g*8 + rh*4 + v];
            }
            __syncthreads();
            if (wave < 4) {
                #pragma unroll
                for (int g = 0; g < 4; g++)
                    #pragma unroll
                    for (int rh = 0; rh < 2; rh++)
                        #pragma unroll
                        for (int v = 0; v < 4; v++)
                            red[wave][lane][g*8 + rh*4 + v] = acc[g][rh][v];
            }
            __syncthreads();

            // balanced epilogue: 512 threads x 1 output element
            int r  = tid >> 4;          // 0..31 local row
            int cc = tid & 15;          // local col
            int rh = r >> 4;
            int r16 = r & 15;
            int kg2 = r16 >> 2, v2 = r16 & 3;
            int ln = kg2 * 16 + cc;
            int idx0 = rh * 4 + v2;
            float s[4];
            #pragma unroll
            for (int g = 0; g < 4; g++) {
                float a = 0.f;
                #pragma unroll
                for (int w = 0; w < 4; w++) a += red[w][ln][g*8 + idx0];
                s[g] = a;
            }
            int jh = colbase + cc;
            int n  = rt * 32 + r;
            float xi = s[0] + bvec[jh];
            float xf = s[1] + bvec[1024 + jh];
            float xo = s[2] + bvec[2048 + jh];
            float xg = s[3] + bvec[3072 + jh];
            float ig = 1.f / (1.f + expf(-xi));
            float fg = 1.f / (1.f + expf(-xf));
            float og = 1.f / (1.f + expf(-xo));
            float gg = tanhf(xg);
            long idx = (long)n * H_ + jh;
            float cn = fg * cbuf[idx] + ig * gg;
            float hn = og * tanhf(cn);
            cbuf[idx] = cn;
            hbuf[idx] = hn;
            hout[idx] = f2bf(hn);
            out[((long)n * T_ + t) * H_ + jh] = hn;
        }
        grid.sync();
    }
}

// ---------------------------------------------------------------- launch ----

extern "C" void kernel_launch(void* const* d_in, const int* in_sizes, int n_in,
                              void* d_out, int out_size, void* d_ws, size_t ws_size,
                              hipStream_t stream) {
    const float* x     = (const float*)d_in[0];
    const float* A     = (const float*)d_in[1];
    const float* Wx    = (const float*)d_in[2];
    const float* Wh    = (const float*)d_in[3];
    const float* Wattn = (const float*)d_in[4];
    const float* b     = (const float*)d_in[5];
    float* out = (float*)d_out;

    char* ws = (char*)d_ws;
    size_t off = 0;
    auto alloc = [&](size_t bytes) -> void* {
        void* p = ws + off;
        off += (bytes + 255) & ~(size_t)255;
        return p;
    };
    unsigned short* xbf    = (unsigned short*)alloc((size_t)N_ * T_ * D_ * 2);
    unsigned short* Wt     = (unsigned short*)alloc((size_t)G4_ * KTOT * 2);
    float*          hbuf   = (float*)alloc((size_t)N_ * H_ * 4);
    float*          cbuf   = (float*)alloc((size_t)N_ * H_ * 4);
    unsigned short* hbf0   = (unsigned short*)alloc((size_t)N_ * H_ * 2);
    unsigned short* hbf1   = (unsigned short*)alloc((size_t)N_ * H_ * 2);
    unsigned short* attnbf = (unsigned short*)alloc((size_t)N_ * H_ * 2);

    // prep
    k_convert_x<<<dim3((N_ * T_ * D_) / (256 * 8)), dim3(256), 0, stream>>>(x, xbf);
    k_transpose<<<dim3(G4_ / 32, D_ / 32), dim3(32, 8), 0, stream>>>(Wx,    Wt, D_, G4_, (long)KTOT, 0L);
    k_transpose<<<dim3(G4_ / 32, H_ / 32), dim3(32, 8), 0, stream>>>(Wh,    Wt, H_, G4_, (long)KTOT, 1024L);
    k_transpose<<<dim3(G4_ / 32, H_ / 32), dim3(32, 8), 0, stream>>>(Wattn, Wt, H_, G4_, (long)KTOT, 2048L);
    k_h0<<<dim3((N_ * H_) / 256), dim3(256), 0, stream>>>(A, hbuf, cbuf, hbf0);

    // persistent cooperative recurrence: all 64 steps in one launch
    int unused = 0;
    void* args[] = {(void*)&xbf, (void*)&hbf0, (void*)&hbf1, (void*)&attnbf,
                    (void*)&Wt, (void*)&b, (void*)&A, (void*)&hbuf, (void*)&cbuf,
                    (void*)&out, (void*)&unused};
    hipLaunchCooperativeKernel((const void*)k_persist, dim3(256), dim3(512),
                               args, 0, stream);
}

// Round 6
// 3283.991 us; speedup vs baseline: 1.5073x; 1.5073x over previous
//
#include <hip/hip_runtime.h>
#include <hip/hip_bf16.h>
#include <cmath>

// Problem constants
#define N_   128
#define T_   64
#define D_   1024
#define H_   1024
#define G4_  4096   // 4*H
#define KTOT 3072   // D + H + H (segments: x | h | attn)

typedef short bf16x8 __attribute__((ext_vector_type(8)));
typedef float f32x4  __attribute__((ext_vector_type(4)));

__device__ __forceinline__ unsigned short f2bf(float f) {
    union { float f; unsigned int u; } v; v.f = f;
    unsigned int r = (v.u + 0x7FFFu + ((v.u >> 16) & 1u)) >> 16;  // RNE
    return (unsigned short)r;
}

// ---------------------------------------------------------------- prep ----

__global__ void k_convert_x(const float* __restrict__ x, unsigned short* __restrict__ xbf) {
    long i = ((long)blockIdx.x * blockDim.x + threadIdx.x) * 8;
    float4 a = *(const float4*)(x + i);
    float4 b = *(const float4*)(x + i + 4);
    union { unsigned short s[8]; uint4 v; } o;
    o.s[0] = f2bf(a.x); o.s[1] = f2bf(a.y); o.s[2] = f2bf(a.z); o.s[3] = f2bf(a.w);
    o.s[4] = f2bf(b.x); o.s[5] = f2bf(b.y); o.s[6] = f2bf(b.z); o.s[7] = f2bf(b.w);
    *(uint4*)(xbf + i) = o.v;
}

// out[c][ocoff + r] = bf16(in[r][c]); in is R x C (f32), out rows have stride ors.
__global__ void k_transpose(const float* __restrict__ in, unsigned short* __restrict__ out,
                            int R, int C, long ors, long ocoff) {
    __shared__ float tile[32][33];
    int c0 = blockIdx.x * 32, r0 = blockIdx.y * 32;
    int tx = threadIdx.x, ty = threadIdx.y;  // (32, 8)
    for (int yy = ty; yy < 32; yy += 8) {
        int r = r0 + yy, c = c0 + tx;
        if (r < R && c < C) tile[yy][tx] = in[(long)r * C + c];
    }
    __syncthreads();
    for (int yy = ty; yy < 32; yy += 8) {
        int oc = c0 + yy;    // out row  (orig col)
        int orr = r0 + tx;   // out col  (orig row)
        if (oc < C && orr < R) out[(long)oc * ors + ocoff + orr] = f2bf(tile[tx][yy]);
    }
}

// h0[n][j] = mean_p A[n][j][p];  c0 = h0;  also bf16 copy
__global__ void k_h0(const float* __restrict__ A, float* __restrict__ h,
                     float* __restrict__ c, unsigned short* __restrict__ hbf) {
    long id = (long)blockIdx.x * blockDim.x + threadIdx.x;  // 0 .. 128*1024-1
    const float4* ap = (const float4*)(A + id * 16);
    float s = 0.f;
    #pragma unroll
    for (int q = 0; q < 4; q++) { float4 v = ap[q]; s += v.x + v.y + v.z + v.w; }
    float m = s * (1.0f / 16.0f);
    h[id] = m; c[id] = m; hbf[id] = f2bf(m);
}

// ------------------------------------------------------------- per step ----

// scores -> softmax -> attn (fp32). One block (512 thr) per n; A read ONCE,
// rows kept in registers for the weighted-sum pass.  (R3-verbatim, proven)
__global__ __launch_bounds__(512)
void k_score(const float* __restrict__ A, const float* __restrict__ h,
             unsigned short* __restrict__ attnbf) {
    int n = blockIdx.x;
    int tid = threadIdx.x;            // 0..511
    int wave = tid >> 6, lane = tid & 63;
    const float* An = A + (long)n * (H_ * 16);
    const float* hn = h + (long)n * H_;

    int h0 = tid * 2;                 // this thread's two H rows
    float4 row[2][4];
    float acc[16];
    #pragma unroll
    for (int p = 0; p < 16; p++) acc[p] = 0.f;
    #pragma unroll
    for (int u = 0; u < 2; u++) {
        float hv = hn[h0 + u];
        const float4* ap = (const float4*)(An + (long)(h0 + u) * 16);
        #pragma unroll
        for (int q = 0; q < 4; q++) {
            float4 v = ap[q];
            row[u][q] = v;
            acc[q*4+0] += hv * v.x; acc[q*4+1] += hv * v.y;
            acc[q*4+2] += hv * v.z; acc[q*4+3] += hv * v.w;
        }
    }
    // wave shuffle reduce (64 lanes)
    #pragma unroll
    for (int off = 32; off > 0; off >>= 1) {
        #pragma unroll
        for (int p = 0; p < 16; p++) acc[p] += __shfl_xor(acc[p], off);
    }
    __shared__ float sred[8][16];
    __shared__ float wsh[16];
    if (lane == 0) {
        #pragma unroll
        for (int p = 0; p < 16; p++) sred[wave][p] = acc[p];
    }
    __syncthreads();
    if (tid < 16) {
        float s = 0.f;
        #pragma unroll
        for (int w = 0; w < 8; w++) s += sred[w][tid];
        wsh[tid] = s * (1.0f / 32.0f);   // /sqrt(H)
    }
    __syncthreads();
    float w[16];
    {
        float m = -1e30f;
        #pragma unroll
        for (int p = 0; p < 16; p++) { w[p] = wsh[p]; m = fmaxf(m, w[p]); }
        float sum = 0.f;
        #pragma unroll
        for (int p = 0; p < 16; p++) { w[p] = expf(w[p] - m); sum += w[p]; }
        float inv = 1.0f / sum;
        #pragma unroll
        for (int p = 0; p < 16; p++) w[p] *= inv;
    }
    #pragma unroll
    for (int u = 0; u < 2; u++) {
        float s = 0.f;
        #pragma unroll
        for (int q = 0; q < 4; q++) {
            float4 v = row[u][q];
            s += w[q*4+0]*v.x + w[q*4+1]*v.y + w[q*4+2]*v.z + w[q*4+3]*v.w;
        }
        attnbf[(long)n * H_ + h0 + u] = f2bf(s);
    }
}

// Fused gate GEMM: act = [xt|h|attn] @ Wt^T + b, then LSTM update.
// grid (64 jt, 4 rt), block 512 = 8 waves. wave = (gate g, row-half rh):
// each wave owns a complete 16x16 output tile over FULL K=3072 — no
// cross-wave K reduce, ONE barrier (act exchange, 8.7KB LDS).
// 96 iters x {1 A-load + 1 B-load -> 1 MFMA}; A deduped 4x (gate waves) and
// B 2x (row-half waves) by L1 (same CU). Per-block unique L2 traffic
// identical to R3 (B=393KB, A=196KB). c/bias prefetched at entry.
// XCD = bid%8 = jt%8: per-XCD Wt slice (3.1MB) L2-resident across steps.
__global__ __launch_bounds__(512)
void k_step(const unsigned short* __restrict__ xbf,     // [N][T][D]
            const unsigned short* __restrict__ hbf_in,  // [N][H]
            const unsigned short* __restrict__ attnbf,  // [N][H]
            const unsigned short* __restrict__ Wt,      // [4096][3072]
            const float* __restrict__ bvec,             // [4096]
            float* __restrict__ c, float* __restrict__ h,
            unsigned short* __restrict__ hbf_out,
            float* __restrict__ out, int t) {
    int wv   = threadIdx.x >> 6;   // 0..7
    int lane = threadIdx.x & 63;
    int g    = wv & 3;             // gate
    int rh   = wv >> 2;            // row half (0/1)
    int cl   = lane & 15;          // MFMA col (jh) / B row within tile
    int kg   = lane >> 4;          // MFMA k-group
    int colbase = blockIdx.x * 16; // jh base
    int rowbase = blockIdx.y * 32; // n base

    // ---- prefetch epilogue operands (no in-step deps) ----
    int tid  = threadIdx.x;
    int nloc = tid >> 4;           // 0..31
    int jl   = tid & 15;
    int jh_e = colbase + jl;
    long idx_e = (long)(rowbase + nloc) * H_ + jh_e;
    float c_old = c[idx_e];
    float b0 = bvec[jh_e], b1 = bvec[1024 + jh_e];
    float b2 = bvec[2048 + jh_e], b3 = bvec[3072 + jh_e];

    // ---- GEMM: one 16x16 tile per wave, full K ----
    f32x4 acc = (f32x4){0.f, 0.f, 0.f, 0.f};
    int r0 = rowbase + rh * 16 + cl;
    const unsigned short* a0[3];
    a0[0] = xbf    + ((long)r0 * T_ + t) * D_ + kg * 8;
    a0[1] = hbf_in + (long)r0 * H_          + kg * 8;
    a0[2] = attnbf + (long)r0 * H_          + kg * 8;
    const unsigned short* bp = Wt + (long)(g * 1024 + colbase + cl) * KTOT + kg * 8;

    #pragma unroll
    for (int seg = 0; seg < 3; seg++) {
        const unsigned short* ap = a0[seg];
        long koff = (long)seg * 1024;
        #pragma unroll 8
        for (int k0 = 0; k0 < 1024; k0 += 32) {
            bf16x8 a  = *(const bf16x8*)(ap + k0);
            bf16x8 bb = *(const bf16x8*)(bp + koff + k0);
            acc = __builtin_amdgcn_mfma_f32_16x16x32_bf16(a, bb, acc, 0, 0, 0);
        }
    }

    // ---- act exchange: one barrier ----
    __shared__ float act[4][32][17];
    #pragma unroll
    for (int v = 0; v < 4; v++)
        act[g][rh * 16 + kg * 4 + v][cl] = acc[v];   // C/D row = 4*kg + v
    __syncthreads();

    // ---- balanced epilogue: 512 threads x 1 (n, jh) output ----
    float xi = act[0][nloc][jl] + b0;
    float xf = act[1][nloc][jl] + b1;
    float xo = act[2][nloc][jl] + b2;
    float xg = act[3][nloc][jl] + b3;
    float ig = 1.f / (1.f + expf(-xi));
    float fg = 1.f / (1.f + expf(-xf));
    float og = 1.f / (1.f + expf(-xo));
    float gg = tanhf(xg);
    float cn = fg * c_old + ig * gg;
    float hn = og * tanhf(cn);
    int n = rowbase + nloc;
    c[idx_e] = cn;
    h[idx_e] = hn;
    hbf_out[idx_e] = f2bf(hn);
    out[((long)n * T_ + t) * H_ + jh_e] = hn;
}

// ---------------------------------------------------------------- launch ----

extern "C" void kernel_launch(void* const* d_in, const int* in_sizes, int n_in,
                              void* d_out, int out_size, void* d_ws, size_t ws_size,
                              hipStream_t stream) {
    const float* x     = (const float*)d_in[0];
    const float* A     = (const float*)d_in[1];
    const float* Wx    = (const float*)d_in[2];
    const float* Wh    = (const float*)d_in[3];
    const float* Wattn = (const float*)d_in[4];
    const float* b     = (const float*)d_in[5];
    float* out = (float*)d_out;

    char* ws = (char*)d_ws;
    size_t off = 0;
    auto alloc = [&](size_t bytes) -> void* {
        void* p = ws + off;
        off += (bytes + 255) & ~(size_t)255;
        return p;
    };
    unsigned short* xbf    = (unsigned short*)alloc((size_t)N_ * T_ * D_ * 2);
    unsigned short* Wt     = (unsigned short*)alloc((size_t)G4_ * KTOT * 2);
    float*          hbuf   = (float*)alloc((size_t)N_ * H_ * 4);
    float*          cbuf   = (float*)alloc((size_t)N_ * H_ * 4);
    unsigned short* hbf0   = (unsigned short*)alloc((size_t)N_ * H_ * 2);
    unsigned short* hbf1   = (unsigned short*)alloc((size_t)N_ * H_ * 2);
    unsigned short* attnbf = (unsigned short*)alloc((size_t)N_ * H_ * 2);

    // prep
    k_convert_x<<<dim3((N_ * T_ * D_) / (256 * 8)), dim3(256), 0, stream>>>(x, xbf);
    k_transpose<<<dim3(G4_ / 32, D_ / 32), dim3(32, 8), 0, stream>>>(Wx,    Wt, D_, G4_, (long)KTOT, 0L);
    k_transpose<<<dim3(G4_ / 32, H_ / 32), dim3(32, 8), 0, stream>>>(Wh,    Wt, H_, G4_, (long)KTOT, 1024L);
    k_transpose<<<dim3(G4_ / 32, H_ / 32), dim3(32, 8), 0, stream>>>(Wattn, Wt, H_, G4_, (long)KTOT, 2048L);
    k_h0<<<dim3((N_ * H_) / 256), dim3(256), 0, stream>>>(A, hbuf, cbuf, hbf0);

    // recurrence
    for (int t = 0; t < T_; t++) {
        unsigned short* hin  = (t & 1) ? hbf1 : hbf0;
        unsigned short* hout = (t & 1) ? hbf0 : hbf1;
        k_score<<<dim3(N_), dim3(512), 0, stream>>>(A, hbuf, attnbf);
        k_step<<<dim3(64, 4), dim3(512), 0, stream>>>(xbf, hin, attnbf, Wt, b,
                                                      cbuf, hbuf, hout, out, t);
    }
}

// Round 7
// 2317.599 us; speedup vs baseline: 2.1359x; 1.4170x over previous
//
#include <hip/hip_runtime.h>
#include <hip/hip_bf16.h>
#include <cmath>

// Problem constants
#define N_   128
#define T_   64
#define D_   1024
#define H_   1024
#define G4_  4096   // 4*H
#define KTOT 3072   // D + H + H (segments: x | h | attn)

typedef short bf16x8 __attribute__((ext_vector_type(8)));
typedef float f32x4  __attribute__((ext_vector_type(4)));

__device__ __forceinline__ unsigned short f2bf(float f) {
    union { float f; unsigned int u; } v; v.f = f;
    unsigned int r = (v.u + 0x7FFFu + ((v.u >> 16) & 1u)) >> 16;  // RNE
    return (unsigned short)r;
}

// ---------------------------------------------------------------- prep ----

__global__ void k_convert_x(const float* __restrict__ x, unsigned short* __restrict__ xbf) {
    long i = ((long)blockIdx.x * blockDim.x + threadIdx.x) * 8;
    float4 a = *(const float4*)(x + i);
    float4 b = *(const float4*)(x + i + 4);
    union { unsigned short s[8]; uint4 v; } o;
    o.s[0] = f2bf(a.x); o.s[1] = f2bf(a.y); o.s[2] = f2bf(a.z); o.s[3] = f2bf(a.w);
    o.s[4] = f2bf(b.x); o.s[5] = f2bf(b.y); o.s[6] = f2bf(b.z); o.s[7] = f2bf(b.w);
    *(uint4*)(xbf + i) = o.v;
}

// out[c][ocoff + r] = bf16(in[r][c]); in is R x C (f32), out rows have stride ors.
__global__ void k_transpose(const float* __restrict__ in, unsigned short* __restrict__ out,
                            int R, int C, long ors, long ocoff) {
    __shared__ float tile[32][33];
    int c0 = blockIdx.x * 32, r0 = blockIdx.y * 32;
    int tx = threadIdx.x, ty = threadIdx.y;  // (32, 8)
    for (int yy = ty; yy < 32; yy += 8) {
        int r = r0 + yy, c = c0 + tx;
        if (r < R && c < C) tile[yy][tx] = in[(long)r * C + c];
    }
    __syncthreads();
    for (int yy = ty; yy < 32; yy += 8) {
        int oc = c0 + yy;    // out row  (orig col)
        int orr = r0 + tx;   // out col  (orig row)
        if (oc < C && orr < R) out[(long)oc * ors + ocoff + orr] = f2bf(tile[tx][yy]);
    }
}

// h0 = mean_p A; c0 = h0; bf16 h0 into Abuf0 h-segment
__global__ void k_h0(const float* __restrict__ A, float* __restrict__ h,
                     float* __restrict__ c, unsigned short* __restrict__ Abuf0) {
    long id = (long)blockIdx.x * blockDim.x + threadIdx.x;  // 0 .. 128*1024-1
    const float4* ap = (const float4*)(A + id * 16);
    float s = 0.f;
    #pragma unroll
    for (int q = 0; q < 4; q++) { float4 v = ap[q]; s += v.x + v.y + v.z + v.w; }
    float m = s * (1.0f / 16.0f);
    h[id] = m; c[id] = m;
    long n = id >> 10, j = id & 1023;
    Abuf0[n * KTOT + 1024 + j] = f2bf(m);
}

// ------------------------------------------------------------- per step ----

// scores -> softmax -> attn (fp32); writes attn AND copies xt into Abuf_t.
// One block (512 thr) per n; A read ONCE (rows kept in registers).
__global__ __launch_bounds__(512)
void k_score(const float* __restrict__ A, const float* __restrict__ h,
             const unsigned short* __restrict__ xbf,
             unsigned short* __restrict__ Abuf, int t) {
    int n = blockIdx.x;
    int tid = threadIdx.x;            // 0..511
    int wave = tid >> 6, lane = tid & 63;
    const float* An = A + (long)n * (H_ * 16);
    const float* hn = h + (long)n * H_;

    // copy xt segment: 128 threads x 16B = 2048B
    if (tid < 128) {
        *(uint4*)(Abuf + (long)n * KTOT + tid * 8) =
            *(const uint4*)(xbf + ((long)n * T_ + t) * D_ + tid * 8);
    }

    int h0 = tid * 2;                 // this thread's two H rows
    float4 row[2][4];
    float acc[16];
    #pragma unroll
    for (int p = 0; p < 16; p++) acc[p] = 0.f;
    #pragma unroll
    for (int u = 0; u < 2; u++) {
        float hv = hn[h0 + u];
        const float4* ap = (const float4*)(An + (long)(h0 + u) * 16);
        #pragma unroll
        for (int q = 0; q < 4; q++) {
            float4 v = ap[q];
            row[u][q] = v;
            acc[q*4+0] += hv * v.x; acc[q*4+1] += hv * v.y;
            acc[q*4+2] += hv * v.z; acc[q*4+3] += hv * v.w;
        }
    }
    #pragma unroll
    for (int off = 32; off > 0; off >>= 1) {
        #pragma unroll
        for (int p = 0; p < 16; p++) acc[p] += __shfl_xor(acc[p], off);
    }
    __shared__ float sred[8][16];
    __shared__ float wsh[16];
    if (lane == 0) {
        #pragma unroll
        for (int p = 0; p < 16; p++) sred[wave][p] = acc[p];
    }
    __syncthreads();
    if (tid < 16) {
        float s = 0.f;
        #pragma unroll
        for (int w = 0; w < 8; w++) s += sred[w][tid];
        wsh[tid] = s * (1.0f / 32.0f);   // /sqrt(H)
    }
    __syncthreads();
    float w[16];
    {
        float m = -1e30f;
        #pragma unroll
        for (int p = 0; p < 16; p++) { w[p] = wsh[p]; m = fmaxf(m, w[p]); }
        float sum = 0.f;
        #pragma unroll
        for (int p = 0; p < 16; p++) { w[p] = expf(w[p] - m); sum += w[p]; }
        float inv = 1.0f / sum;
        #pragma unroll
        for (int p = 0; p < 16; p++) w[p] *= inv;
    }
    #pragma unroll
    for (int u = 0; u < 2; u++) {
        float s = 0.f;
        #pragma unroll
        for (int q = 0; q < 4; q++) {
            float4 v = row[u][q];
            s += w[q*4+0]*v.x + w[q*4+1]*v.y + w[q*4+2]*v.z + w[q*4+3]*v.w;
        }
        Abuf[(long)n * KTOT + 2048 + h0 + u] = f2bf(s);
    }
}

// Fused gate GEMM: act = Abuf_in @ Wt^T + b, then LSTM update.
// grid (64 jt, 4 rt), block 512 = 8 waves = (rh: 2 row-halves) x (ks: 4 K-quarters).
// Each wave: 16 rows x 16 jh x ALL 4 gates over K=768 (24 iters, 1A+4B -> 4 MFMA).
// PF=4 register prefetch pipeline (static indices only). One 4-way LDS K-reduce
// + act exchange (2 barriers). h written as bf16 into Abuf_out h-segment.
// XCD = bid%8 = jt%8: per-XCD Wt slice (3.1MB) L2-resident across steps.
__global__ __launch_bounds__(512, 2)
void k_step(const unsigned short* __restrict__ Ain,   // [N][KTOT]
            unsigned short* __restrict__ Aout,        // [N][KTOT] (h-seg written)
            const unsigned short* __restrict__ Wt,    // [4096][3072]
            const float* __restrict__ bvec,           // [4096]
            float* __restrict__ c, float* __restrict__ h,
            float* __restrict__ out, int t) {
    int wv   = threadIdx.x >> 6;   // 0..7
    int lane = threadIdx.x & 63;
    int rh   = wv & 1;             // row half
    int ks   = wv >> 1;            // K quarter
    int cl   = lane & 15;          // MFMA col (jh) / B row within tile
    int kg   = lane >> 4;          // MFMA k-group
    int colbase = blockIdx.x * 16; // jh base
    int rowbase = blockIdx.y * 32; // n base

    // ---- epilogue operand prefetch ----
    int tid  = threadIdx.x;
    int nloc = tid >> 4;           // 0..31
    int jl   = tid & 15;
    int jh_e = colbase + jl;
    long idx_e = (long)(rowbase + nloc) * H_ + jh_e;
    float c_old = c[idx_e];
    float b0 = bvec[jh_e], b1 = bvec[1024 + jh_e];
    float b2 = bvec[2048 + jh_e], b3 = bvec[3072 + jh_e];

    // ---- GEMM with PF=4 register pipeline ----
    f32x4 acc[4];
    #pragma unroll
    for (int g = 0; g < 4; g++) acc[g] = (f32x4){0.f, 0.f, 0.f, 0.f};

    int r0 = rowbase + rh * 16 + cl;
    const unsigned short* ap = Ain + (long)r0 * KTOT + ks * 768 + kg * 8;
    const unsigned short* bp[4];
    #pragma unroll
    for (int g = 0; g < 4; g++)
        bp[g] = Wt + (long)(g * 1024 + colbase + cl) * KTOT + ks * 768 + kg * 8;

    bf16x8 abuf[4];
    bf16x8 bbuf[4][4];
    #pragma unroll
    for (int i = 0; i < 4; i++) {
        abuf[i] = *(const bf16x8*)(ap + i * 32);
        #pragma unroll
        for (int g = 0; g < 4; g++)
            bbuf[i][g] = *(const bf16x8*)(bp[g] + i * 32);
    }
    // 24 iters total: 5 batches with prefetch + 1 drain batch
    for (int k0 = 0; k0 < 20; k0 += 4) {
        #pragma unroll
        for (int i = 0; i < 4; i++) {
            #pragma unroll
            for (int g = 0; g < 4; g++)
                acc[g] = __builtin_amdgcn_mfma_f32_16x16x32_bf16(abuf[i], bbuf[i][g], acc[g], 0, 0, 0);
            int nk = k0 + 4 + i;
            abuf[i] = *(const bf16x8*)(ap + nk * 32);
            #pragma unroll
            for (int g = 0; g < 4; g++)
                bbuf[i][g] = *(const bf16x8*)(bp[g] + nk * 32);
        }
    }
    #pragma unroll
    for (int i = 0; i < 4; i++) {
        #pragma unroll
        for (int g = 0; g < 4; g++)
            acc[g] = __builtin_amdgcn_mfma_f32_16x16x32_bf16(abuf[i], bbuf[i][g], acc[g], 0, 0, 0);
    }

    // ---- 4-way K reduce + act exchange ----
    __shared__ float red[3][2][64][17];   // ks 1..3 partials, pad 17
    __shared__ float act[4][32][17];
    if (ks != 0) {
        #pragma unroll
        for (int g = 0; g < 4; g++)
            #pragma unroll
            for (int v = 0; v < 4; v++)
                red[ks - 1][rh][lane][g * 4 + v] = acc[g][v];
    }
    __syncthreads();
    if (ks == 0) {
        #pragma unroll
        for (int g = 0; g < 4; g++) {
            #pragma unroll
            for (int v = 0; v < 4; v++) {
                float s = acc[g][v] + red[0][rh][lane][g * 4 + v]
                        + red[1][rh][lane][g * 4 + v] + red[2][rh][lane][g * 4 + v];
                act[g][rh * 16 + kg * 4 + v][cl] = s;   // C/D row = 4*kg + v
            }
        }
    }
    __syncthreads();

    // ---- balanced epilogue: 512 threads x 1 (n, jh) output ----
    float xi = act[0][nloc][jl] + b0;
    float xf = act[1][nloc][jl] + b1;
    float xo = act[2][nloc][jl] + b2;
    float xg = act[3][nloc][jl] + b3;
    float ig = 1.f / (1.f + expf(-xi));
    float fg = 1.f / (1.f + expf(-xf));
    float og = 1.f / (1.f + expf(-xo));
    float gg = tanhf(xg);
    float cn = fg * c_old + ig * gg;
    float hn = og * tanhf(cn);
    int n = rowbase + nloc;
    c[idx_e] = cn;
    h[idx_e] = hn;
    Aout[(long)n * KTOT + 1024 + jh_e] = f2bf(hn);
    out[((long)n * T_ + t) * H_ + jh_e] = hn;
}

// ---------------------------------------------------------------- launch ----

extern "C" void kernel_launch(void* const* d_in, const int* in_sizes, int n_in,
                              void* d_out, int out_size, void* d_ws, size_t ws_size,
                              hipStream_t stream) {
    const float* x     = (const float*)d_in[0];
    const float* A     = (const float*)d_in[1];
    const float* Wx    = (const float*)d_in[2];
    const float* Wh    = (const float*)d_in[3];
    const float* Wattn = (const float*)d_in[4];
    const float* b     = (const float*)d_in[5];
    float* out = (float*)d_out;

    char* ws = (char*)d_ws;
    size_t off = 0;
    auto alloc = [&](size_t bytes) -> void* {
        void* p = ws + off;
        off += (bytes + 255) & ~(size_t)255;
        return p;
    };
    unsigned short* xbf   = (unsigned short*)alloc((size_t)N_ * T_ * D_ * 2);
    unsigned short* Wt    = (unsigned short*)alloc((size_t)G4_ * KTOT * 2);
    float*          hbuf  = (float*)alloc((size_t)N_ * H_ * 4);
    float*          cbuf  = (float*)alloc((size_t)N_ * H_ * 4);
    unsigned short* Abuf0 = (unsigned short*)alloc((size_t)N_ * KTOT * 2);
    unsigned short* Abuf1 = (unsigned short*)alloc((size_t)N_ * KTOT * 2);

    // prep
    k_convert_x<<<dim3((N_ * T_ * D_) / (256 * 8)), dim3(256), 0, stream>>>(x, xbf);
    k_transpose<<<dim3(G4_ / 32, D_ / 32), dim3(32, 8), 0, stream>>>(Wx,    Wt, D_, G4_, (long)KTOT, 0L);
    k_transpose<<<dim3(G4_ / 32, H_ / 32), dim3(32, 8), 0, stream>>>(Wh,    Wt, H_, G4_, (long)KTOT, 1024L);
    k_transpose<<<dim3(G4_ / 32, H_ / 32), dim3(32, 8), 0, stream>>>(Wattn, Wt, H_, G4_, (long)KTOT, 2048L);
    k_h0<<<dim3((N_ * H_) / 256), dim3(256), 0, stream>>>(A, hbuf, cbuf, Abuf0);

    // recurrence
    for (int t = 0; t < T_; t++) {
        unsigned short* Ain  = (t & 1) ? Abuf1 : Abuf0;
        unsigned short* Aout = (t & 1) ? Abuf0 : Abuf1;
        k_score<<<dim3(N_), dim3(512), 0, stream>>>(A, hbuf, xbf, Ain, t);
        k_step<<<dim3(64, 4), dim3(512), 0, stream>>>(Ain, Aout, Wt, b,
                                                      cbuf, hbuf, out, t);
    }
}

// Round 8
// 1858.081 us; speedup vs baseline: 2.6641x; 1.2473x over previous
//
#include <hip/hip_runtime.h>
#include <hip/hip_bf16.h>
#include <cmath>

// Problem constants
#define N_   128
#define T_   64
#define D_   1024
#define H_   1024
#define G4_  4096   // 4*H
#define K2   2048   // recurrent GEMM K: x | h

typedef short bf16x8 __attribute__((ext_vector_type(8)));
typedef float f32x4  __attribute__((ext_vector_type(4)));

__device__ __forceinline__ unsigned short f2bf(float f) {
    union { float f; unsigned int u; } v; v.f = f;
    unsigned int r = (v.u + 0x7FFFu + ((v.u >> 16) & 1u)) >> 16;  // RNE
    return (unsigned short)r;
}
__device__ __forceinline__ float bf2f(unsigned short s) {
    union { unsigned int u; float f; } v; v.u = ((unsigned int)s) << 16;
    return v.f;
}

// ---------------------------------------------------------------- prep ----

__global__ void k_convert_x(const float* __restrict__ x, unsigned short* __restrict__ xbf) {
    long i = ((long)blockIdx.x * blockDim.x + threadIdx.x) * 8;
    float4 a = *(const float4*)(x + i);
    float4 b = *(const float4*)(x + i + 4);
    union { unsigned short s[8]; uint4 v; } o;
    o.s[0] = f2bf(a.x); o.s[1] = f2bf(a.y); o.s[2] = f2bf(a.z); o.s[3] = f2bf(a.w);
    o.s[4] = f2bf(b.x); o.s[5] = f2bf(b.y); o.s[6] = f2bf(b.z); o.s[7] = f2bf(b.w);
    *(uint4*)(xbf + i) = o.v;
}

// out[c][ocoff + r] = bf16(in[r][c]); in is R x C (f32), out rows stride ors.
__global__ void k_transpose(const float* __restrict__ in, unsigned short* __restrict__ out,
                            int R, int C, long ors, long ocoff) {
    __shared__ float tile[32][33];
    int c0 = blockIdx.x * 32, r0 = blockIdx.y * 32;
    int tx = threadIdx.x, ty = threadIdx.y;  // (32, 8)
    for (int yy = ty; yy < 32; yy += 8) {
        int r = r0 + yy, c = c0 + tx;
        if (r < R && c < C) tile[yy][tx] = in[(long)r * C + c];
    }
    __syncthreads();
    for (int yy = ty; yy < 32; yy += 8) {
        int oc = c0 + yy, orr = r0 + tx;
        if (oc < C && orr < R) out[(long)oc * ors + ocoff + orr] = f2bf(tile[tx][yy]);
    }
}

// Af2[n][h][p] bf16 (A layout) and AfT[(n*16+p)][h] bf16 (transposed).
// grid (128, 16): block = (n, 64-h chunk), 256 thr.
__global__ void k_afdual(const float* __restrict__ A, unsigned short* __restrict__ Af2,
                         unsigned short* __restrict__ AfT) {
    int n = blockIdx.x, hc = blockIdx.y * 64;
    int tid = threadIdx.x;
    int hl = tid >> 2, p4 = (tid & 3) * 4;    // 64 h-rows x 4 p's each
    __shared__ float ldsT[16][65];
    const float* src = A + ((long)n * H_ + hc + hl) * 16 + p4;
    float4 v = *(const float4*)src;
    // Af2 (same layout, bf16)
    unsigned short o[4] = {f2bf(v.x), f2bf(v.y), f2bf(v.z), f2bf(v.w)};
    *(uint2*)(Af2 + ((long)n * H_ + hc + hl) * 16 + p4) = *(uint2*)o;
    ldsT[p4 + 0][hl] = v.x; ldsT[p4 + 1][hl] = v.y;
    ldsT[p4 + 2][hl] = v.z; ldsT[p4 + 3][hl] = v.w;
    __syncthreads();
    int p = tid >> 4, hs = (tid & 15) * 4;   // 16 p-rows x 64 h
    unsigned short q[4] = {f2bf(ldsT[p][hs]), f2bf(ldsT[p][hs + 1]),
                           f2bf(ldsT[p][hs + 2]), f2bf(ldsT[p][hs + 3])};
    *(uint2*)(AfT + ((long)n * 16 + p) * (long)H_ + hc + hs) = *(uint2*)q;
}

// h0 = mean_p A; c0 = h0; bf16 copy into hbf0
__global__ void k_h0(const float* __restrict__ A, float* __restrict__ h,
                     float* __restrict__ c, unsigned short* __restrict__ hbf0) {
    long id = (long)blockIdx.x * blockDim.x + threadIdx.x;
    const float4* ap = (const float4*)(A + id * 16);
    float s = 0.f;
    #pragma unroll
    for (int q = 0; q < 4; q++) { float4 v = ap[q]; s += v.x + v.y + v.z + v.w; }
    float m = s * (1.0f / 16.0f);
    h[id] = m; c[id] = m; hbf0[id] = f2bf(m);
}

// AW[(n*4096 + j)*16 + p] bf16 = sum_h AfT[n*16+p][h] * WattnT[j][h]
// grid (64 jt, 128 mt): 16 rows x 64 cols, K=1024. 256 thr, 4 waves (K-quarters).
__global__ __launch_bounds__(256, 2)
void k_aw(const unsigned short* __restrict__ AfT, const unsigned short* __restrict__ WattnT,
          unsigned short* __restrict__ AW) {
    int wv = threadIdx.x >> 6, lane = threadIdx.x & 63;
    int cl = lane & 15, kg = lane >> 4;
    int mbase = blockIdx.y * 16, jbase = blockIdx.x * 64;

    f32x4 acc[4];
    #pragma unroll
    for (int s = 0; s < 4; s++) acc[s] = (f32x4){0.f, 0.f, 0.f, 0.f};
    const unsigned short* ap = AfT + (long)(mbase + cl) * H_ + wv * 256 + kg * 8;
    const unsigned short* bp[4];
    #pragma unroll
    for (int s = 0; s < 4; s++)
        bp[s] = WattnT + (long)(jbase + s * 16 + cl) * H_ + wv * 256 + kg * 8;
    #pragma unroll
    for (int k0 = 0; k0 < 256; k0 += 32) {
        bf16x8 a = *(const bf16x8*)(ap + k0);
        #pragma unroll
        for (int s = 0; s < 4; s++) {
            bf16x8 bb = *(const bf16x8*)(bp[s] + k0);
            acc[s] = __builtin_amdgcn_mfma_f32_16x16x32_bf16(a, bb, acc[s], 0, 0, 0);
        }
    }
    __shared__ float red[3][64][17];
    __shared__ float act[4][16][17];
    if (wv != 0) {
        #pragma unroll
        for (int s = 0; s < 4; s++)
            #pragma unroll
            for (int v = 0; v < 4; v++) red[wv - 1][lane][s * 4 + v] = acc[s][v];
    }
    __syncthreads();
    if (wv == 0) {
        #pragma unroll
        for (int s = 0; s < 4; s++)
            #pragma unroll
            for (int v = 0; v < 4; v++) {
                float t = acc[s][v] + red[0][lane][s*4+v] + red[1][lane][s*4+v] + red[2][lane][s*4+v];
                act[s][kg * 4 + v][cl] = t;
            }
    }
    __syncthreads();
    int mloc = threadIdx.x >> 4, jl = threadIdx.x & 15;
    if (mloc < 16) {
        int m = mbase + mloc, n = m >> 4, p = m & 15;
        #pragma unroll
        for (int s = 0; s < 4; s++) {
            int j = jbase + s * 16 + jl;
            AW[((long)n * G4_ + j) * 16 + p] = f2bf(act[s][mloc][jl]);
        }
    }
}

// ------------------------------------------------------------- per step ----

// t=0 full score: w[n][16] = softmax(h0 . Af / 32). One block per n.
__global__ __launch_bounds__(512)
void k_score0(const float* __restrict__ A, const float* __restrict__ h,
              float* __restrict__ wbuf) {
    int n = blockIdx.x;
    int tid = threadIdx.x;
    int wave = tid >> 6, lane = tid & 63;
    const float* An = A + (long)n * (H_ * 16);
    const float* hn = h + (long)n * H_;
    int h0 = tid * 2;
    float acc[16];
    #pragma unroll
    for (int p = 0; p < 16; p++) acc[p] = 0.f;
    #pragma unroll
    for (int u = 0; u < 2; u++) {
        float hv = hn[h0 + u];
        const float4* ap = (const float4*)(An + (long)(h0 + u) * 16);
        #pragma unroll
        for (int q = 0; q < 4; q++) {
            float4 v = ap[q];
            acc[q*4+0] += hv * v.x; acc[q*4+1] += hv * v.y;
            acc[q*4+2] += hv * v.z; acc[q*4+3] += hv * v.w;
        }
    }
    #pragma unroll
    for (int off = 32; off > 0; off >>= 1) {
        #pragma unroll
        for (int p = 0; p < 16; p++) acc[p] += __shfl_xor(acc[p], off);
    }
    __shared__ float sred[8][16];
    __shared__ float wsh[16];
    if (lane == 0) {
        #pragma unroll
        for (int p = 0; p < 16; p++) sred[wave][p] = acc[p];
    }
    __syncthreads();
    if (tid < 16) {
        float s = 0.f;
        #pragma unroll
        for (int w = 0; w < 8; w++) s += sred[w][tid];
        wsh[tid] = s * (1.0f / 32.0f);
    }
    __syncthreads();
    if (tid < 16) {
        float w[16], m = -1e30f;
        #pragma unroll
        for (int p = 0; p < 16; p++) { w[p] = wsh[p]; m = fmaxf(m, w[p]); }
        float sum = 0.f;
        #pragma unroll
        for (int p = 0; p < 16; p++) { w[p] = expf(w[p] - m); sum += w[p]; }
        wbuf[n * 16 + tid] = w[tid] / sum;
    }
}

// t>=1 tiny score: reduce partial[n][p][64] -> softmax -> w[n][16]. 128 blocks x 64.
__global__ __launch_bounds__(64)
void k_score_tiny(const float* __restrict__ partial, float* __restrict__ wbuf) {
    int n = blockIdx.x;
    int lane = threadIdx.x;
    int p = lane & 15, c4 = lane >> 4;
    const float* src = partial + ((long)n * 16 + p) * 64 + c4 * 16;
    float s = 0.f;
    #pragma unroll
    for (int q = 0; q < 16; q++) s += src[q];
    s += __shfl_xor(s, 16);
    s += __shfl_xor(s, 32);
    s *= (1.0f / 32.0f);
    float m = s;
    #pragma unroll
    for (int off = 1; off < 16; off <<= 1) m = fmaxf(m, __shfl_xor(m, off));
    float e = expf(s - m);
    float sum = e;
    #pragma unroll
    for (int off = 1; off < 16; off <<= 1) sum += __shfl_xor(sum, off);
    if (c4 == 0) wbuf[n * 16 + p] = e / sum;
}

// Fused step: act = [xt|h] @ WxhT^T + w.AW + b; gates; c,h update; score partials.
// grid (64 jt, 8 rt), 256 thr = 4 waves (K-quarters of 512). M=16 rows.
__global__ __launch_bounds__(256, 2)
void k_step(const unsigned short* __restrict__ xbf,     // [N][T][D]
            const unsigned short* __restrict__ hbf_in,  // [N][H]
            unsigned short* __restrict__ hbf_out,       // [N][H]
            const unsigned short* __restrict__ WxhT,    // [4096][2048]
            const unsigned short* __restrict__ AW,      // [N][4096][16]
            const unsigned short* __restrict__ Af2,     // [N][H][16]
            const float* __restrict__ wbuf,             // [N][16]
            const float* __restrict__ bvec,             // [4096]
            float* __restrict__ c,
            float* __restrict__ partial,                // [N][16][64]
            float* __restrict__ out, int t) {
    int wv = threadIdx.x >> 6;    // K-quarter 0..3
    int lane = threadIdx.x & 63;
    int cl = lane & 15, kg = lane >> 4;
    int colbase = blockIdx.x * 16;
    int rowbase = blockIdx.y * 16;
    int jt = blockIdx.x;

    // ---- GEMM: 16 rows x (16 jh x 4 gates), K-window 512 per wave ----
    f32x4 acc[4];
    #pragma unroll
    for (int g = 0; g < 4; g++) acc[g] = (f32x4){0.f, 0.f, 0.f, 0.f};
    int r0 = rowbase + cl;
    const unsigned short* ap = (wv < 2)
        ? xbf    + ((long)r0 * T_ + t) * D_ + (wv & 1) * 512 + kg * 8
        : hbf_in + (long)r0 * H_           + (wv & 1) * 512 + kg * 8;
    const unsigned short* bp[4];
    #pragma unroll
    for (int g = 0; g < 4; g++)
        bp[g] = WxhT + (long)(g * 1024 + colbase + cl) * K2 + wv * 512 + kg * 8;

    #pragma unroll
    for (int k0 = 0; k0 < 512; k0 += 32) {
        bf16x8 a = *(const bf16x8*)(ap + k0);
        #pragma unroll
        for (int g = 0; g < 4; g++) {
            bf16x8 bb = *(const bf16x8*)(bp[g] + k0);
            acc[g] = __builtin_amdgcn_mfma_f32_16x16x32_bf16(a, bb, acc[g], 0, 0, 0);
        }
    }

    // ---- 4-way K reduce ----
    __shared__ float red[3][64][17];
    __shared__ float act[4][16][17];
    if (wv != 0) {
        #pragma unroll
        for (int g = 0; g < 4; g++)
            #pragma unroll
            for (int v = 0; v < 4; v++) red[wv - 1][lane][g * 4 + v] = acc[g][v];
    }
    __syncthreads();
    if (wv == 0) {
        #pragma unroll
        for (int g = 0; g < 4; g++)
            #pragma unroll
            for (int v = 0; v < 4; v++) {
                float s = acc[g][v] + red[0][lane][g*4+v] + red[1][lane][g*4+v] + red[2][lane][g*4+v];
                act[g][kg * 4 + v][cl] = s;   // C/D row = 4*kg + v
            }
    }
    __syncthreads();

    // ---- epilogue: 256 thr x 1 (n, jh) cell ----
    int tid = threadIdx.x;
    int nloc = tid >> 4, jl = tid & 15;
    int n = rowbase + nloc, jh = colbase + jl;

    // w[16] for this n
    float wv16[16];
    #pragma unroll
    for (int p = 0; p < 16; p++) wv16[p] = wbuf[n * 16 + p];

    float s4[4];
    #pragma unroll
    for (int g = 0; g < 4; g++) {
        int j = g * 1024 + jh;
        // attn contribution: sum_p w[p] * AW[n][j][p]  (32B contiguous)
        const unsigned short* awp = AW + ((long)n * G4_ + j) * 16;
        bf16x8 aw0 = *(const bf16x8*)(awp);
        bf16x8 aw1 = *(const bf16x8*)(awp + 8);
        float at = 0.f;
        #pragma unroll
        for (int p = 0; p < 8; p++) at += wv16[p] * bf2f((unsigned short)aw0[p]);
        #pragma unroll
        for (int p = 0; p < 8; p++) at += wv16[8 + p] * bf2f((unsigned short)aw1[p]);
        s4[g] = act[g][nloc][jl] + at + bvec[j];
    }
    float ig = 1.f / (1.f + expf(-s4[0]));
    float fg = 1.f / (1.f + expf(-s4[1]));
    float og = 1.f / (1.f + expf(-s4[2]));
    float gg = tanhf(s4[3]);
    long idx = (long)n * H_ + jh;
    float cn = fg * c[idx] + ig * gg;
    float hn = og * tanhf(cn);
    c[idx] = cn;
    hbf_out[idx] = f2bf(hn);
    out[((long)n * T_ + t) * H_ + jh] = hn;

    // ---- score partials for step t+1: sp[p] = sum_{jh in tile} hn * Af2[n][jh][p]
    const unsigned short* afp = Af2 + ((long)n * H_ + jh) * 16;
    bf16x8 af0 = *(const bf16x8*)(afp);
    bf16x8 af1 = *(const bf16x8*)(afp + 8);
    float sp[16];
    #pragma unroll
    for (int p = 0; p < 8; p++) sp[p]     = hn * bf2f((unsigned short)af0[p]);
    #pragma unroll
    for (int p = 0; p < 8; p++) sp[8 + p] = hn * bf2f((unsigned short)af1[p]);
    #pragma unroll
    for (int off = 1; off < 16; off <<= 1) {
        #pragma unroll
        for (int p = 0; p < 16; p++) sp[p] += __shfl_xor(sp[p], off);
    }
    float outv = 0.f;
    #pragma unroll
    for (int p = 0; p < 16; p++) if (jl == p) outv = sp[p];
    partial[((long)n * 16 + jl) * 64 + jt] = outv;
}

// ---------------------------------------------------------------- launch ----

extern "C" void kernel_launch(void* const* d_in, const int* in_sizes, int n_in,
                              void* d_out, int out_size, void* d_ws, size_t ws_size,
                              hipStream_t stream) {
    const float* x     = (const float*)d_in[0];
    const float* A     = (const float*)d_in[1];
    const float* Wx    = (const float*)d_in[2];
    const float* Wh    = (const float*)d_in[3];
    const float* Wattn = (const float*)d_in[4];
    const float* b     = (const float*)d_in[5];
    float* out = (float*)d_out;

    char* ws = (char*)d_ws;
    size_t off = 0;
    auto alloc = [&](size_t bytes) -> void* {
        void* p = ws + off;
        off += (bytes + 255) & ~(size_t)255;
        return p;
    };
    unsigned short* xbf    = (unsigned short*)alloc((size_t)N_ * T_ * D_ * 2);
    unsigned short* WxhT   = (unsigned short*)alloc((size_t)G4_ * K2 * 2);
    unsigned short* WattnT = (unsigned short*)alloc((size_t)G4_ * H_ * 2);
    unsigned short* AfT    = (unsigned short*)alloc((size_t)N_ * 16 * H_ * 2);
    unsigned short* Af2    = (unsigned short*)alloc((size_t)N_ * H_ * 16 * 2);
    unsigned short* AW     = (unsigned short*)alloc((size_t)N_ * G4_ * 16 * 2);
    float*          hbuf   = (float*)alloc((size_t)N_ * H_ * 4);
    float*          cbuf   = (float*)alloc((size_t)N_ * H_ * 4);
    unsigned short* hbf0   = (unsigned short*)alloc((size_t)N_ * H_ * 2);
    unsigned short* hbf1   = (unsigned short*)alloc((size_t)N_ * H_ * 2);
    float*          wbuf   = (float*)alloc((size_t)N_ * 16 * 4);
    float*          partial= (float*)alloc((size_t)N_ * 16 * 64 * 4);

    // prep
    k_convert_x<<<dim3((N_ * T_ * D_) / (256 * 8)), dim3(256), 0, stream>>>(x, xbf);
    k_transpose<<<dim3(G4_ / 32, D_ / 32), dim3(32, 8), 0, stream>>>(Wx,    WxhT,   D_, G4_, (long)K2, 0L);
    k_transpose<<<dim3(G4_ / 32, H_ / 32), dim3(32, 8), 0, stream>>>(Wh,    WxhT,   H_, G4_, (long)K2, 1024L);
    k_transpose<<<dim3(G4_ / 32, H_ / 32), dim3(32, 8), 0, stream>>>(Wattn, WattnT, H_, G4_, (long)H_, 0L);
    k_afdual<<<dim3(N_, 16), dim3(256), 0, stream>>>(A, Af2, AfT);
    k_h0<<<dim3((N_ * H_) / 256), dim3(256), 0, stream>>>(A, hbuf, cbuf, hbf0);
    k_aw<<<dim3(G4_ / 64, (N_ * 16) / 16), dim3(256), 0, stream>>>(AfT, WattnT, AW);

    // recurrence
    for (int t = 0; t < T_; t++) {
        unsigned short* hin  = (t & 1) ? hbf1 : hbf0;
        unsigned short* hout = (t & 1) ? hbf0 : hbf1;
        if (t == 0)
            k_score0<<<dim3(N_), dim3(512), 0, stream>>>(A, hbuf, wbuf);
        else
            k_score_tiny<<<dim3(N_), dim3(64), 0, stream>>>(partial, wbuf);
        k_step<<<dim3(64, 8), dim3(256), 0, stream>>>(xbf, hin, hout, WxhT, AW, Af2,
                                                      wbuf, b, cbuf, partial, out, t);
    }
}